// Round 7
// baseline (25.293 us; speedup 1.0000x reference)
//
#include <hip/hip_runtime.h>

// B=32, C=3, IMG=256, N=65536, K=49152, JMAX=16384
#define NTOT 65536
#define CCH 3
#define BB 32
#define KK 49152
#define JMAXV 16384
#define K1_FWHT 768      // (b,c,hi-group) transform blocks
#define K1_TOTAL 1024    // + 256 table-build blocks

struct F3 { float x, y, z; };

__device__ __forceinline__ void bfly(float& a, float& b) {
    float s = a + b, d = a - b; a = s; b = d;
}

// Single DPP exchange (VALU pipe)
template<int CTRL>
__device__ __forceinline__ float dppx(float w) {
    return __uint_as_float((unsigned)__builtin_amdgcn_update_dpp(
        0, (int)__float_as_uint(w), CTRL, 0xF, 0xF, true));
}

// Per-lane butterfly signs: s_m = (lane & m) ? -1 : +1.
// Every stage is then w' = p + s*w  (exact fma with +-1).
struct Sg { float s1, s2, s4, s8, s16, s32; };

// mask 1: quad_perm [1,0,3,2] = xor1
__device__ __forceinline__ float st1(float w, float s) {
    float p = dppx<0xB1>(w); return fmaf(s, w, p);
}
// mask 2: quad_perm [2,3,0,1] = xor2
__device__ __forceinline__ float st2(float w, float s) {
    float p = dppx<0x4E>(w); return fmaf(s, w, p);
}
// mask 4: quad_perm [3,2,1,0] (xor3) then row_half_mirror (xor7) => xor4
__device__ __forceinline__ float st4(float w, float s) {
    float p = dppx<0x141>(dppx<0x1B>(w)); return fmaf(s, w, p);
}
// mask 8: row_half_mirror (xor7) then row_mirror (xor15) => xor8
__device__ __forceinline__ float st8(float w, float s) {
    float p = dppx<0x140>(dppx<0x141>(w)); return fmaf(s, w, p);
}
// mask 16: permlane16_swap (VALU)
__device__ __forceinline__ float st16(float w, float s) {
#if __has_builtin(__builtin_amdgcn_permlane16_swap)
    unsigned u = __float_as_uint(w);
    auto r = __builtin_amdgcn_permlane16_swap(u, u, false, false);
    return fmaf(s, __uint_as_float(r[1]), __uint_as_float(r[0]));
#else
    float p = __shfl_xor(w, 16); return fmaf(s, w, p);
#endif
}
// mask 32: permlane32_swap (VALU)
__device__ __forceinline__ float st32(float w, float s) {
#if __has_builtin(__builtin_amdgcn_permlane32_swap)
    unsigned u = __float_as_uint(w);
    auto r = __builtin_amdgcn_permlane32_swap(u, u, false, false);
    return fmaf(s, __uint_as_float(r[1]), __uint_as_float(r[0]));
#else
    float p = __shfl_xor(w, 32); return fmaf(s, w, p);
#endif
}

// 6 lane-exchange butterfly stages (masks 1..32) on 4 values (ILP).
__device__ __forceinline__ void lane_fwht6(float& w0, float& w1, float& w2,
                                           float& w3, const Sg& g) {
    w0 = st1(w0, g.s1);  w1 = st1(w1, g.s1);  w2 = st1(w2, g.s1);  w3 = st1(w3, g.s1);
    w0 = st2(w0, g.s2);  w1 = st2(w1, g.s2);  w2 = st2(w2, g.s2);  w3 = st2(w3, g.s2);
    w0 = st4(w0, g.s4);  w1 = st4(w1, g.s4);  w2 = st4(w2, g.s4);  w3 = st4(w3, g.s4);
    w0 = st8(w0, g.s8);  w1 = st8(w1, g.s8);  w2 = st8(w2, g.s8);  w3 = st8(w3, g.s8);
    w0 = st16(w0, g.s16); w1 = st16(w1, g.s16); w2 = st16(w2, g.s16); w3 = st16(w3, g.s16);
    w0 = st32(w0, g.s32); w1 = st32(w1, g.s32); w2 = st32(w2, g.s32); w3 = st32(w3, g.s32);
}

__device__ __forceinline__ Sg mk_signs(int lane) {
    Sg g;
    g.s1  = (lane & 1)  ? -1.0f : 1.0f;
    g.s2  = (lane & 2)  ? -1.0f : 1.0f;
    g.s4  = (lane & 4)  ? -1.0f : 1.0f;
    g.s8  = (lane & 8)  ? -1.0f : 1.0f;
    g.s16 = (lane & 16) ? -1.0f : 1.0f;
    g.s32 = (lane & 32) ? -1.0f : 1.0f;
    return g;
}

__device__ __forceinline__ unsigned short f2bf(float f) {
    return (unsigned short)((__float_as_uint(f) + 0x8000u) >> 16);
}

// K1: lo-FWHT of 256-float segments, output TRANSPOSED as bf16
// mid_t[b][c][lo][hi]. Lane l holds lo = 4l+r. One float4/lane per segment.
// LDS [pi][lo]: write one ds_write_b128/iter (conflict-free), read b32 at
// bank=t%32 (2 lanes/bank, free). Thread t stores row lo=t, 32 his = 64B.
// Tail blocks build jtab_t[lo*256+hi] = j or -1.
__global__ __launch_bounds__(256) void k1_lo_t(
        const float* __restrict__ vec, unsigned short* __restrict__ midt,
        const int* __restrict__ perm, int* __restrict__ jtabt) {
    __shared__ unsigned lds32[16 * 256];   // 16 KB
    int bx = blockIdx.x, t = threadIdx.x;
    if (bx < K1_FWHT) {
        int rc  = bx >> 3;          // b*3+c
        int hi0 = (bx & 7) * 32;
        const float* src = vec + (size_t)rc * NTOT;
        int lane = t & 63;
        int w    = t >> 6;
        Sg g = mk_signs(lane);
#pragma unroll
        for (int k = 0; k < 4; ++k) {      // 4 segment-pairs per wave
            int hi = hi0 + w * 8 + 2 * k;
            float4 a4 = *reinterpret_cast<const float4*>(src + (size_t)hi * 256 + 4 * lane);
            float4 b4 = *reinterpret_cast<const float4*>(src + (size_t)(hi + 1) * 256 + 4 * lane);
            float a0 = a4.x, a1 = a4.y, a2 = a4.z, a3 = a4.w;
            float b0 = b4.x, b1 = b4.y, b2 = b4.z, b3 = b4.w;

            bfly(a0, a1); bfly(a2, a3);           // lo bit 0
            bfly(a0, a2); bfly(a1, a3);           // lo bit 1
            lane_fwht6(a0, a1, a2, a3, g);        // lo bits 2..7
            bfly(b0, b1); bfly(b2, b3);
            bfly(b0, b2); bfly(b1, b3);
            lane_fwht6(b0, b1, b2, b3, g);

            int pi = w * 4 + k;                   // hi-pair index 0..15
            uint4 pk;
            pk.x = (unsigned)f2bf(a0) | ((unsigned)f2bf(b0) << 16);
            pk.y = (unsigned)f2bf(a1) | ((unsigned)f2bf(b1) << 16);
            pk.z = (unsigned)f2bf(a2) | ((unsigned)f2bf(b2) << 16);
            pk.w = (unsigned)f2bf(a3) | ((unsigned)f2bf(b3) << 16);
            *reinterpret_cast<uint4*>(&lds32[pi * 256 + 4 * lane]) = pk;
        }
        __syncthreads();

        // thread t: output row lo=t, 32 his = 16 uints = 4x uint4 (64B line)
        unsigned* d32 = reinterpret_cast<unsigned*>(
            midt + (size_t)rc * NTOT + (size_t)t * 256 + hi0);
#pragma unroll
        for (int q4 = 0; q4 < 4; ++q4) {
            uint4 v;
            v.x = lds32[(q4 * 4 + 0) * 256 + t];
            v.y = lds32[(q4 * 4 + 1) * 256 + t];
            v.z = lds32[(q4 * 4 + 2) * 256 + t];
            v.w = lds32[(q4 * 4 + 3) * 256 + t];
            reinterpret_cast<uint4*>(d32)[q4] = v;
        }
    } else {
        int j = (bx - K1_FWHT) * 256 + t;
        int n = perm[j];
        jtabt[(n & 255) * 256 + (n >> 8)] = (j < JMAXV) ? j : -1;
    }
}

// K2: hi-FWHT straight from mid_t (coalesced, LDS-free), fused scatter.
// Wave = one (b,lo), all 3 channels. Lane l holds hi = 4l+r (uint2/lane);
// jtab row as int4/lane. hi bits 0,1 in-register, bits 2..7 lane stages.
__global__ __launch_bounds__(256) void k2_hi_scatter(
        const unsigned short* __restrict__ midt, const int* __restrict__ jtabt,
        const float* __restrict__ sing, float* __restrict__ out) {
    int gid  = blockIdx.x * 256 + threadIdx.x;
    int lane = gid & 63;
    int wid  = gid >> 6;          // 0..8191
    int b    = wid >> 8;
    int lo   = wid & 255;
    Sg g = mk_signs(lane);

    float v[3][4];
#pragma unroll
    for (int c = 0; c < 3; ++c) {
        const uint2* p = reinterpret_cast<const uint2*>(
            midt + ((size_t)(b * 3 + c)) * NTOT + (size_t)lo * 256);
        uint2 u = p[lane];            // his 4l..4l+3 (bf16-packed)
        float w0 = __uint_as_float(u.x << 16);
        float w1 = __uint_as_float(u.x & 0xFFFF0000u);
        float w2 = __uint_as_float(u.y << 16);
        float w3 = __uint_as_float(u.y & 0xFFFF0000u);
        bfly(w0, w1); bfly(w2, w3);        // hi bit 0
        bfly(w0, w2); bfly(w1, w3);        // hi bit 1
        lane_fwht6(w0, w1, w2, w3, g);     // hi bits 2..7
        v[c][0] = w0; v[c][1] = w1; v[c][2] = w2; v[c][3] = w3;
    }

    int4 jq = reinterpret_cast<const int4*>(jtabt + (size_t)lo * 256)[lane];
    int jj[4] = { jq.x, jq.y, jq.z, jq.w };   // j for hi = 4l+0..3

    float* outb = out + (size_t)b * KK;
#pragma unroll
    for (int i = 0; i < 4; ++i) {
        int j = jj[i];
        if (j >= 0) {
            F3 s = *reinterpret_cast<const F3*>(sing + 3 * j);
            F3 o;
            o.x = (s.x * (1.0f / 256.0f)) * v[0][i];
            o.y = (s.y * (1.0f / 256.0f)) * v[1][i];
            o.z = (s.z * (1.0f / 256.0f)) * v[2][i];
            *reinterpret_cast<F3*>(outb + 3 * j) = o;
        }
    }
}

extern "C" void kernel_launch(void* const* d_in, const int* in_sizes, int n_in,
                              void* d_out, int out_size, void* d_ws, size_t ws_size,
                              hipStream_t stream) {
    const float* vec  = (const float*)d_in[0];
    const float* sing = (const float*)d_in[1];
    const int*   perm = (const int*)d_in[2];
    float* out = (float*)d_out;

    int*            jtabt = (int*)d_ws;                               // 256 KB
    unsigned short* midt  = (unsigned short*)((char*)d_ws + 262144);  // 12.6 MB bf16

    k1_lo_t<<<K1_TOTAL, 256, 0, stream>>>(vec, midt, perm, jtabt);
    k2_hi_scatter<<<BB * 256 / 4, 256, 0, stream>>>(midt, jtabt, sing, out);
}